// Round 4
// baseline (836.541 us; speedup 1.0000x reference)
//
#include <hip/hip_runtime.h>
#include <stdint.h>

// ---------------------------------------------------------------------------
// JAX threefry2x32 (20 rounds), bit-exact port of jax/_src/prng.py
// ---------------------------------------------------------------------------
static __host__ __device__ inline uint32_t rotl32(uint32_t x, int r) {
  return (x << r) | (x >> (32 - r));
}

static __host__ __device__ inline void tf2x32(uint32_t k0, uint32_t k1,
                                              uint32_t x0, uint32_t x1,
                                              uint32_t& o0, uint32_t& o1) {
  uint32_t k2 = k0 ^ k1 ^ 0x1BD11BDAu;
#define TFR(a) { x0 += x1; x1 = rotl32(x1, a); x1 ^= x0; }
  x0 += k0; x1 += k1;
  TFR(13) TFR(15) TFR(26) TFR(6)
  x0 += k1; x1 += k2 + 1u;
  TFR(17) TFR(29) TFR(16) TFR(24)
  x0 += k2; x1 += k0 + 2u;
  TFR(13) TFR(15) TFR(26) TFR(6)
  x0 += k0; x1 += k1 + 3u;
  TFR(17) TFR(29) TFR(16) TFR(24)
  x0 += k1; x1 += k2 + 4u;
  TFR(13) TFR(15) TFR(26) TFR(6)
  x0 += k2; x1 += k0 + 5u;
#undef TFR
  o0 = x0; o1 = x1;
}

static __device__ inline uint32_t fold_bits(uint32_t k0, uint32_t k1, uint32_t ctr) {
  uint32_t a, b;
  tf2x32(k0, k1, 0u, ctr, a, b);
  return a ^ b;
}

// Partial-sort cutoff: candidates have m = bits>>9 < CUT (i.e. bits < 2^29).
// Expected candidates 4.19M >= R~3.36M with ~440 sigma margin.
#define CUT       (1u << 20)
#define NBINS     256u
#define BINREG    17408u               // per-bin pairs region (mean 16384, +8 sigma)
#define CAND_CAP  (4718592u)           // sorted2 capacity (mean 4.19M, ~160 sigma)
#define POOLCAP   5120u                // per-block LDS candidate pool (mean 4096, 17 sigma)
#define ELEMS_K1  32768
#define SORT_CAP_FB (6u * 1024u * 1024u)

// ---------------------------------------------------------------------------
// K1 (mega): per 32768-elem block:
//   - bernoulli mask words + per-block repl count (rsums)
//   - fine histogram buckets[m] (2^20)
//   - LDS candidate pool (m, id|localIdx) -> bin-grouped coalesced pair writes
// pairs rec: {.x = (m_low12<<17)|id17, .y = global index}
// ---------------------------------------------------------------------------
__global__ __launch_bounds__(256) void k_mega(const float* __restrict__ x,
                                              uint64_t* __restrict__ mask,
                                              uint32_t* __restrict__ rsums,
                                              uint32_t* __restrict__ buckets,
                                              uint32_t* __restrict__ binCursor,
                                              uint2* __restrict__ pairs,
                                              uint32_t bk0, uint32_t bk1,
                                              uint32_t sk0, uint32_t sk1,
                                              int n, int doPairs) {
  __shared__ uint32_t pool_m[POOLCAP];   // 20 KB: fine bucket m (20b)
  __shared__ uint32_t pool_b[POOLCAP];   // 20 KB: (id17 << 15) | localIdx15
  __shared__ uint32_t lhist[256], lgbase[256], lcur[256];
  __shared__ uint32_t lpoolCnt;
  __shared__ uint32_t wcnt[4];

  int tid = threadIdx.x, lane = tid & 63, wid = tid >> 6;
  int base = blockIdx.x * ELEMS_K1;
  lhist[tid] = 0;
  if (tid == 0) lpoolCnt = 0;
  __syncthreads();

  uint32_t cnt = 0;
  for (int k = 0; k < ELEMS_K1 / 256; k++) {
    int li = k * 256 + tid;
    int i = base + li;
    bool inb = (i < n);
    float xv = inb ? x[i] : 0.0f;
    bool nonpad = inb && (xv != 0.0f);
    // bernoulli stream
    bool r = false;
    if (inb) {
      uint32_t bb = fold_bits(bk0, bk1, (uint32_t)i);
      float u = __uint_as_float((bb >> 9) | 0x3f800000u) - 1.0f;
      r = (u < 0.1f) && nonpad;
    }
    unsigned long long ball = __ballot(r);
    int wbase = base + k * 256 + wid * 64;
    if (lane == 0 && wbase < n) mask[wbase / 64] = (uint64_t)ball;
    cnt += r ? 1u : 0u;
    // shuffle-key stream
    uint32_t m = 0; bool cand = false;
    if (nonpad) {
      uint32_t bits = fold_bits(sk0, sk1, (uint32_t)i);
      m = bits >> 9;
      cand = (m < CUT);
    }
    if (cand) atomicAdd((unsigned int*)&buckets[m], 1u);
    // wave-aggregated pool append
    unsigned long long ball2 = __ballot(cand);
    uint32_t cnt2 = (uint32_t)__popcll(ball2);
    uint32_t pbase = 0;
    if (lane == 0 && cnt2) pbase = atomicAdd(&lpoolCnt, cnt2);
    pbase = __shfl(pbase, 0);
    if (cand) {
      uint32_t slot = pbase + (uint32_t)__popcll(ball2 & ((1ull << lane) - 1ull));
      if (slot < POOLCAP) {
        pool_m[slot] = m;
        pool_b[slot] = (((uint32_t)xv) << 15) | (uint32_t)li;
      }
      atomicAdd(&lhist[m >> 12], 1u);
    }
  }
  // rsums
  for (int d = 32; d >= 1; d >>= 1) cnt += __shfl_down(cnt, d, 64);
  if (lane == 0) wcnt[wid] = cnt;
  __syncthreads();
  if (tid == 0) rsums[blockIdx.x] = wcnt[0] + wcnt[1] + wcnt[2] + wcnt[3];
  // reserve per-bin runs (binCursor starts at 0; regions are fixed-stride)
  uint32_t h = lhist[tid];
  lgbase[tid] = h ? atomicAdd((unsigned int*)&binCursor[tid], h) : 0u;
  lcur[tid] = 0u;
  __syncthreads();
  if (!doPairs) return;
  uint32_t pc = lpoolCnt; if (pc > POOLCAP) pc = POOLCAP;
  for (uint32_t j = tid; j < pc; j += 256) {
    uint32_t m = pool_m[j];
    uint32_t b = pool_b[j];
    uint32_t bin = m >> 12;
    uint32_t off = atomicAdd(&lcur[bin], 1u) + lgbase[bin];
    if (off < BINREG) {
      uint32_t gi = (uint32_t)base + (b & 0x7FFFu);
      pairs[(size_t)bin * BINREG + off] = make_uint2(((m & 4095u) << 17) | (b >> 15), gi);
    }
  }
}

// ---------------------------------------------------------------------------
// Scan helpers (proven)
// ---------------------------------------------------------------------------
__global__ void k_chunksum(const uint32_t* __restrict__ data, uint32_t* __restrict__ sums, int n) {
  __shared__ uint32_t wsum[4];
  int tid = threadIdx.x, lane = tid & 63, wid = tid >> 6;
  int base = blockIdx.x * 4096;
  uint32_t s = 0;
  for (int k = 0; k < 16; k++) {
    int i = base + k * 256 + tid;
    if (i < n) s += data[i];
  }
  for (int d = 32; d >= 1; d >>= 1) s += __shfl_down(s, d, 64);
  if (lane == 0) wsum[wid] = s;
  __syncthreads();
  if (tid == 0) sums[blockIdx.x] = wsum[0] + wsum[1] + wsum[2] + wsum[3];
}

// exclusive scan in place; also writes data[n] = total (alloc n+1!)
__global__ void k_scan_single(uint32_t* __restrict__ data, int n) {
  __shared__ uint32_t wsum[4];
  int tid = threadIdx.x, lane = tid & 63, wid = tid >> 6;
  uint32_t running = 0;
  for (int base = 0; base < n; base += 256) {
    int i = base + tid;
    uint32_t v = (i < n) ? data[i] : 0u;
    uint32_t incl = v;
    for (int d = 1; d < 64; d <<= 1) {
      uint32_t t = __shfl_up(incl, (unsigned)d, 64);
      if (lane >= d) incl += t;
    }
    if (lane == 63) wsum[wid] = incl;
    __syncthreads();
    uint32_t woff = 0, tot = 0;
    for (int w = 0; w < 4; w++) { uint32_t s = wsum[w]; if (w < wid) woff += s; tot += s; }
    if (i < n) data[i] = running + woff + (incl - v);
    running += tot;
    __syncthreads();
  }
  if (tid == 0) data[n] = running;
}

__global__ void k_scan_apply(uint32_t* __restrict__ data, const uint32_t* __restrict__ sums, int n) {
  __shared__ uint32_t wsum[4];
  int tid = threadIdx.x, lane = tid & 63, wid = tid >> 6;
  int base = blockIdx.x * 4096;
  uint32_t running = sums[blockIdx.x];
  for (int k = 0; k < 16; k++) {
    int i = base + k * 256 + tid;
    uint32_t v = (i < n) ? data[i] : 0u;
    uint32_t incl = v;
    for (int d = 1; d < 64; d <<= 1) {
      uint32_t t = __shfl_up(incl, (unsigned)d, 64);
      if (lane >= d) incl += t;
    }
    if (lane == 63) wsum[wid] = incl;
    __syncthreads();
    uint32_t woff = 0, tot = 0;
    for (int w = 0; w < 4; w++) { uint32_t s = wsum[w]; if (w < wid) woff += s; tot += s; }
    if (i < n) data[i] = running + woff + (incl - v);
    running += tot;
    __syncthreads();
  }
}

// ---------------------------------------------------------------------------
// Phase B2: one block per bin (sole-owner ~140KB write window -> L2 merge).
// Scatter pairs to exact fine-bucket slots via atomic cursors (unstable within
// bucket; fixed by k_bucket_sort2). No LDS, no threefry.
// ---------------------------------------------------------------------------
__global__ __launch_bounds__(1024) void k_phaseB2(const uint2* __restrict__ pairs,
                                                  const uint32_t* __restrict__ binCursor,
                                                  uint32_t* __restrict__ cursors,
                                                  uint2* __restrict__ sorted2) {
  uint32_t bin = blockIdx.x;
  uint32_t cntb = binCursor[bin];
  if (cntb > BINREG) cntb = BINREG;
  size_t s = (size_t)bin * BINREG;
  for (uint32_t j = threadIdx.x; j < cntb; j += 1024) {
    uint2 p = pairs[s + j];
    uint32_t m = (bin << 12) | (p.x >> 17);
    uint32_t pos = atomicAdd((unsigned int*)&cursors[m], 1u);
    if (pos < CAND_CAP) sorted2[pos] = p;
  }
}

// ---------------------------------------------------------------------------
// Per-bucket tie stabilization by index (.y), global memory, avg 4/bucket.
// After phaseB2, cursors[b] = end of bucket b; start = cursors[b-1].
// ---------------------------------------------------------------------------
__global__ void k_bucket_sort2(const uint32_t* __restrict__ cursors,
                               uint2* __restrict__ sorted2, uint32_t nb) {
  uint32_t b = blockIdx.x * blockDim.x + threadIdx.x;
  if (b >= nb) return;
  uint32_t end = cursors[b];
  uint32_t start = (b == 0) ? 0u : cursors[b - 1];
  if (end > CAND_CAP) end = CAND_CAP;
  if (start > CAND_CAP) start = CAND_CAP;
  if (end - start <= 1u) return;
  for (uint32_t u = start + 1; u < end; u++) {
    uint2 v = sorted2[u];
    uint32_t w = u;
    while (w > start && sorted2[w - 1].y > v.y) { sorted2[w] = sorted2[w - 1]; w--; }
    sorted2[w] = v;
  }
}

// ---------------------------------------------------------------------------
// Fallback (round-2 proven) scatter + bucket sort (index-only)
// ---------------------------------------------------------------------------
__global__ void k_scatter_fb(const float* __restrict__ x, uint32_t* __restrict__ cursors,
                             uint32_t* __restrict__ sortedIdx, uint32_t sk0, uint32_t sk1,
                             int n, uint32_t cap) {
  int i = blockIdx.x * blockDim.x + threadIdx.x;
  if (i >= n) return;
  if (x[i] == 0.0f) return;
  uint32_t m = fold_bits(sk0, sk1, (uint32_t)i) >> 9;
  if (m >= CUT) return;
  uint32_t pos = atomicAdd((unsigned int*)&cursors[m], 1u);
  if (pos < cap) sortedIdx[pos] = (uint32_t)i;
}

__global__ void k_bucket_sort_fb(const uint32_t* __restrict__ cursors,
                                 uint32_t* __restrict__ sortedIdx, uint32_t nb, uint32_t cap) {
  uint32_t b = blockIdx.x * blockDim.x + threadIdx.x;
  if (b >= nb) return;
  uint32_t end = cursors[b];
  uint32_t start = (b == 0) ? 0u : cursors[b - 1];
  if (end > cap) end = cap;
  if (start > cap) start = cap;
  if (end - start <= 1u) return;
  for (uint32_t u = start + 1; u < end; u++) {
    uint32_t v = sortedIdx[u];
    uint32_t w = u;
    while (w > start && sortedIdx[w - 1] > v) { sortedIdx[w] = sortedIdx[w - 1]; w--; }
    sortedIdx[w] = v;
  }
}

// ---------------------------------------------------------------------------
// Final: out[i] = repl ? donor : x[i].  Block covers 32768 elems (matches K1
// blocking so rsums line up).
// direct=1: donor = (float)(sorted2[rank].x & 0x1FFFF) (sequential reads).
// direct=0: donor = x[sortedIdx[rank]] (fallback).
// ---------------------------------------------------------------------------
__global__ __launch_bounds__(256) void k_final(const float* __restrict__ x,
                                               const uint64_t* __restrict__ mask,
                                               const uint32_t* __restrict__ rsums,
                                               const uint32_t* __restrict__ sortedIdx,
                                               const uint2* __restrict__ sorted2, int direct,
                                               float* __restrict__ out, int n) {
  __shared__ uint32_t wcnt[4];
  int tid = threadIdx.x, lane = tid & 63, wid = tid >> 6;
  int base = blockIdx.x * ELEMS_K1;
  uint32_t running = rsums[blockIdx.x];
  for (int k = 0; k < ELEMS_K1 / 256; k++) {
    int i = base + k * 256 + tid;
    int wbase = base + k * 256 + wid * 64;
    uint64_t word = (wbase < n) ? mask[wbase / 64] : 0ull;
    bool r = (word >> lane) & 1ull;
    uint32_t inword = (uint32_t)__popcll(word & ((1ull << lane) - 1ull));
    uint32_t wtot = (uint32_t)__popcll(word);
    if (lane == 0) wcnt[wid] = wtot;
    __syncthreads();
    uint32_t woff = 0, tot = 0;
    for (int w = 0; w < 4; w++) { uint32_t s = wcnt[w]; if (w < wid) woff += s; tot += s; }
    if (i < n) {
      float o = x[i];
      if (r) {
        uint32_t rank = running + woff + inword;
        o = direct ? (float)(sorted2[rank].x & 0x1FFFFu) : x[sortedIdx[rank]];
      }
      out[i] = o;
    }
    running += tot;
    __syncthreads();
  }
}

// ---------------------------------------------------------------------------
extern "C" void kernel_launch(void* const* d_in, const int* in_sizes, int n_in,
                              void* d_out, int out_size, void* d_ws, size_t ws_size,
                              hipStream_t stream) {
  const float* x = (const float*)d_in[0];
  float* out = (float*)d_out;
  int n = in_sizes[0];
  (void)n_in; (void)out_size;

  uint32_t bk0, bk1, sk0, sk1;
  tf2x32(0u, 42u, 0u, 0u, bk0, bk1);
  tf2x32(0u, 42u, 0u, 1u, sk0, sk1);

  int nBlkK = (n + ELEMS_K1 - 1) / ELEMS_K1;   // 1024
  int nChunksB = (int)(CUT / 4096);            // 256

  size_t off = 0;
  auto alloc = [&](size_t bytes) -> void* {
    void* p = (uint8_t*)d_ws + off;
    off += (bytes + 255) & ~(size_t)255;
    return p;
  };
  uint32_t* buckets   = (uint32_t*)alloc((size_t)CUT * 4);                 // 4 MB
  uint32_t* csums     = (uint32_t*)alloc((size_t)(nChunksB + 1) * 4);
  uint32_t* binCursor = (uint32_t*)alloc((size_t)NBINS * 4);
  uint32_t* rsums     = (uint32_t*)alloc((size_t)(nBlkK + 1) * 4);
  uint64_t* mask      = (uint64_t*)alloc((size_t)((n + 63) / 64) * 8);     // 4 MB
  size_t commonOff = off;

  size_t pairsB  = ((size_t)NBINS * BINREG * 8 + 255) & ~(size_t)255;      // 34 MB
  size_t sortedB = ((size_t)CAND_CAP * 8 + 255) & ~(size_t)255;            // 36 MB
  bool useNew = (ws_size >= commonOff + pairsB + sortedB);

  hipMemsetAsync(buckets, 0, (size_t)CUT * 4, stream);
  hipMemsetAsync(binCursor, 0, (size_t)NBINS * 4, stream);

  uint2* pairs = nullptr;
  if (useNew) pairs = (uint2*)alloc(pairsB);

  k_mega<<<nBlkK, 256, 0, stream>>>(x, mask, rsums, buckets, binCursor, pairs,
                                    bk0, bk1, sk0, sk1, n, useNew ? 1 : 0);
  k_chunksum<<<nChunksB, 256, 0, stream>>>(buckets, csums, (int)CUT);
  k_scan_single<<<1, 256, 0, stream>>>(csums, nChunksB);
  k_scan_apply<<<nChunksB, 256, 0, stream>>>(buckets, csums, (int)CUT);
  k_scan_single<<<1, 256, 0, stream>>>(rsums, nBlkK);

  if (useNew) {
    uint2* sorted2 = (uint2*)alloc(sortedB);
    k_phaseB2<<<(int)NBINS, 1024, 0, stream>>>(pairs, binCursor, buckets, sorted2);
    k_bucket_sort2<<<(int)(CUT / 256), 256, 0, stream>>>(buckets, sorted2, CUT);
    k_final<<<nBlkK, 256, 0, stream>>>(x, mask, rsums, nullptr, sorted2, 1, out, n);
  } else {
    uint32_t* sortedIdx = (uint32_t*)alloc((size_t)SORT_CAP_FB * 4);       // 24 MB
    int nThreadBlocks = (n + 255) / 256;
    k_scatter_fb<<<nThreadBlocks, 256, 0, stream>>>(x, buckets, sortedIdx, sk0, sk1, n, SORT_CAP_FB);
    k_bucket_sort_fb<<<(int)(CUT / 256), 256, 0, stream>>>(buckets, sortedIdx, CUT, SORT_CAP_FB);
    k_final<<<nBlkK, 256, 0, stream>>>(x, mask, rsums, sortedIdx, nullptr, 0, out, n);
  }
}